// Round 7
// baseline (139.840 us; speedup 1.0000x reference)
//
#include <hip/hip_runtime.h>

#define BATCH 2
#define EDIM 192
#define NHEAD 6
#define DHEAD 32
#define HH 56
#define WW 56
#define NPIX (HH * WW)   // 3136

// ---------------- NATTEN clamped window start (matches numpy reference) ----
__device__ __forceinline__ int win_start(int i, int length, int K, int dil) {
    int NS = K >> 1;
    if (dil <= 1) {
        int s = i - NS;
        if (s < 0) s = 0;
        if (i + NS >= length) s += length - i - NS - 1;
        return s;
    }
    int ni = i - NS * dil;
    int imodd = i % dil;
    int aa = (length / dil) * dil;
    int bb = length - aa;
    int end_start = (imodd < bb) ? (length - bb + imodd - 2 * NS * dil)
                                 : (aa + imodd - K * dil);
    if (ni < 0) return imodd;
    if (i + NS * dil >= length) return end_start;
    return ni;
}

#define DOT4(a, b) ((a).x * (b).x + (a).y * (b).y + (a).z * (b).z + (a).w * (b).w)

// ============ conv1x1 v3: no LDS, no sync ==================================
// thread = 8 outputs x 2 pixels, full K=192 in-thread (16 indep FMA chains).
// Both x (float2/thread) and w (uniform float4 -> s_load) double-buffered.
// blockIdx.x = o-group (fastest) -> pixel tile shared in L2/L3.

#define CONV_FMA(XV, WV)                                     \
    _Pragma("unroll")                                        \
    for (int o = 0; o < 8; ++o) {                            \
        acc[o][0] = fmaf(XV[0].x, WV[o].x, acc[o][0]);       \
        acc[o][1] = fmaf(XV[0].y, WV[o].x, acc[o][1]);       \
        acc[o][0] = fmaf(XV[1].x, WV[o].y, acc[o][0]);       \
        acc[o][1] = fmaf(XV[1].y, WV[o].y, acc[o][1]);       \
        acc[o][0] = fmaf(XV[2].x, WV[o].z, acc[o][0]);       \
        acc[o][1] = fmaf(XV[2].y, WV[o].z, acc[o][1]);       \
        acc[o][0] = fmaf(XV[3].x, WV[o].w, acc[o][0]);       \
        acc[o][1] = fmaf(XV[3].y, WV[o].w, acc[o][1]);       \
    }

// ---- qkv variant ----------------------------------------------------------
__global__ __launch_bounds__(256) void qkv_conv_kernel(
    const float* __restrict__ x, const float* __restrict__ w,
    const float* __restrict__ bias,
    float* __restrict__ q_pm, float* __restrict__ k_pm,
    float* __restrict__ v_pm, float* __restrict__ v_cm)
{
    const int b  = blockIdx.z;
    const int o0 = blockIdx.x * 8;          // 8 output channels (of 576)
    const int p0 = blockIdx.y * 512;        // 512-pixel tile
    int pb = p0 + threadIdx.x * 2;
    if (pb > NPIX - 2) pb = NPIX - 2;       // clamp loads; writes guarded
    const float* xb = x + (size_t)b * EDIM * NPIX + pb;
    const float* wb = w + (size_t)o0 * EDIM;

    float acc[8][2];
#pragma unroll
    for (int o = 0; o < 8; ++o) { acc[o][0] = 0.f; acc[o][1] = 0.f; }

    float2 xA[4], xB[4];
    float4 wA[8], wB[8];
#pragma unroll
    for (int i = 0; i < 4; ++i)
        xA[i] = *reinterpret_cast<const float2*>(xb + (size_t)i * NPIX);
#pragma unroll
    for (int o = 0; o < 8; ++o)
        wA[o] = *reinterpret_cast<const float4*>(wb + o * EDIM);

    for (int c = 0; c < EDIM; c += 8) {
#pragma unroll
        for (int i = 0; i < 4; ++i)
            xB[i] = *reinterpret_cast<const float2*>(xb + (size_t)(c + 4 + i) * NPIX);
#pragma unroll
        for (int o = 0; o < 8; ++o)
            wB[o] = *reinterpret_cast<const float4*>(wb + o * EDIM + c + 4);
        CONV_FMA(xA, wA);
        if (c + 8 < EDIM) {
#pragma unroll
            for (int i = 0; i < 4; ++i)
                xA[i] = *reinterpret_cast<const float2*>(xb + (size_t)(c + 8 + i) * NPIX);
#pragma unroll
            for (int o = 0; o < 8; ++o)
                wA[o] = *reinterpret_cast<const float4*>(wb + o * EDIM + c + 8);
        }
        CONV_FMA(xB, wB);
    }

    const int m  = o0 / EDIM;               // 0=q,1=k,2=v
    const int hd = (o0 % EDIM) / DHEAD;     // head
    const int d0 = o0 % DHEAD;              // d offset (multiple of 8)
    float* pm = (m == 0 ? q_pm : (m == 1 ? k_pm : v_pm));
    const float ks = (m == 1) ? 0.17677669529663687f : 1.f;   // 32^-0.5

#pragma unroll
    for (int j = 0; j < 2; ++j) {
        const int gp = p0 + threadIdx.x * 2 + j;
        if (gp >= NPIX) continue;
        float vals[8];
#pragma unroll
        for (int o = 0; o < 8; ++o)
            vals[o] = (acc[o][j] + bias[o0 + o]) * ks;
        float* dst = pm + ((size_t)(b * NHEAD + hd) * NPIX + gp) * DHEAD + d0;
        *reinterpret_cast<float4*>(dst)     = make_float4(vals[0], vals[1], vals[2], vals[3]);
        *reinterpret_cast<float4*>(dst + 4) = make_float4(vals[4], vals[5], vals[6], vals[7]);
        if (m == 2) {
            float* vc = v_cm + ((size_t)b * EDIM + hd * DHEAD + d0) * NPIX + gp;
#pragma unroll
            for (int o = 0; o < 8; ++o) vc[(size_t)o * NPIX] = vals[o];
        }
    }
}

// ---- out variant: in = v2_cm + lepe, writes channel-major d_out -----------
__global__ __launch_bounds__(256) void out_conv_kernel(
    const float* __restrict__ v2, const float* __restrict__ lepe,
    const float* __restrict__ w, const float* __restrict__ bias,
    float* __restrict__ out)
{
    const int b  = blockIdx.z;
    const int o0 = blockIdx.x * 8;          // 8 output channels (of 192)
    const int p0 = blockIdx.y * 512;
    int pb = p0 + threadIdx.x * 2;
    if (pb > NPIX - 2) pb = NPIX - 2;
    const float* vb = v2   + (size_t)b * EDIM * NPIX + pb;
    const float* lb = lepe + (size_t)b * EDIM * NPIX + pb;
    const float* wb = w + (size_t)o0 * EDIM;

    float acc[8][2];
#pragma unroll
    for (int o = 0; o < 8; ++o) { acc[o][0] = 0.f; acc[o][1] = 0.f; }

    float2 xA[4], xB[4];
    float4 wA[8], wB[8];
#pragma unroll
    for (int i = 0; i < 4; ++i) {
        const float2 v0 = *reinterpret_cast<const float2*>(vb + (size_t)i * NPIX);
        const float2 l0 = *reinterpret_cast<const float2*>(lb + (size_t)i * NPIX);
        xA[i] = make_float2(v0.x + l0.x, v0.y + l0.y);
    }
#pragma unroll
    for (int o = 0; o < 8; ++o)
        wA[o] = *reinterpret_cast<const float4*>(wb + o * EDIM);

    for (int c = 0; c < EDIM; c += 8) {
#pragma unroll
        for (int i = 0; i < 4; ++i) {
            const float2 v0 = *reinterpret_cast<const float2*>(vb + (size_t)(c + 4 + i) * NPIX);
            const float2 l0 = *reinterpret_cast<const float2*>(lb + (size_t)(c + 4 + i) * NPIX);
            xB[i] = make_float2(v0.x + l0.x, v0.y + l0.y);
        }
#pragma unroll
        for (int o = 0; o < 8; ++o)
            wB[o] = *reinterpret_cast<const float4*>(wb + o * EDIM + c + 4);
        CONV_FMA(xA, wA);
        if (c + 8 < EDIM) {
#pragma unroll
            for (int i = 0; i < 4; ++i) {
                const float2 v0 = *reinterpret_cast<const float2*>(vb + (size_t)(c + 8 + i) * NPIX);
                const float2 l0 = *reinterpret_cast<const float2*>(lb + (size_t)(c + 8 + i) * NPIX);
                xA[i] = make_float2(v0.x + l0.x, v0.y + l0.y);
            }
#pragma unroll
            for (int o = 0; o < 8; ++o)
                wA[o] = *reinterpret_cast<const float4*>(wb + o * EDIM + c + 8);
        }
        CONV_FMA(xB, wB);
    }

#pragma unroll
    for (int j = 0; j < 2; ++j) {
        const int gp = p0 + threadIdx.x * 2 + j;
        if (gp >= NPIX) continue;
#pragma unroll
        for (int o = 0; o < 8; ++o)
            out[((size_t)b * EDIM + o0 + o) * NPIX + gp] = acc[o][j] + bias[o0 + o];
    }
}

// ---------------- depthwise 5x5 LePE on channel-major v --------------------
__global__ __launch_bounds__(256) void lepe_kernel(
    const float* __restrict__ v_cm, const float* __restrict__ w,
    const float* __restrict__ bias, float* __restrict__ out)
{
    const int t = blockIdx.x * 256 + threadIdx.x;
    if (t >= BATCH * EDIM * NPIX) return;
    const int yx = t % NPIX;
    const int bc = t / NPIX;
    const int c = bc % EDIM;
    const int y = yx / WW, x = yx % WW;

    const float* vp = v_cm + (size_t)bc * NPIX;
    const float* wp = w + (size_t)c * 25;
    float acc = bias[c];
#pragma unroll
    for (int dy = 0; dy < 5; ++dy) {
        const int yy = y + dy - 2;
        if (yy < 0 || yy >= HH) continue;
#pragma unroll
        for (int dx = 0; dx < 5; ++dx) {
            const int xx = x + dx - 2;
            if (xx < 0 || xx >= WW) continue;
            acc = fmaf(vp[yy * WW + xx], wp[dy * 5 + dx], acc);
        }
    }
    out[t] = acc;
}

// ---------------- neighborhood attention: coalesced d-quarter split --------
// lane = qs*8 + dg : 8 queries (consecutive yx) x 8 d-quarters (float4 each).
template<int K, int DIL, bool OUT_CM>
__global__ __launch_bounds__(256) void na2d_kernel(
    const float* __restrict__ q, const float* __restrict__ k,
    const float* __restrict__ v, float* __restrict__ out)
{
    const int tid  = blockIdx.x * 256 + threadIdx.x;
    const int lane = threadIdx.x & 63;
    const int dg   = lane & 7;                  // d-quarter
    const int qs   = lane >> 3;                 // query slot in wave
    const int qid  = (tid >> 6) * 8 + qs;       // global query index
    const int yx = qid % NPIX;
    const int bn = qid / NPIX;
    const int y = yx / WW, x = yx % WW;
    const int ys = win_start(y, HH, K, DIL);
    const int xs = win_start(x, WW, K, DIL);

    const float4 qr = *reinterpret_cast<const float4*>(
        q + ((size_t)bn * NPIX + yx) * DHEAD + dg * 4);
    const float* kb = k + (size_t)bn * NPIX * DHEAD + dg * 4;
    const float* vb = v + (size_t)bn * NPIX * DHEAD + dg * 4;

    float m = -3.0e38f, s = 0.f;
    float4 o = make_float4(0.f, 0.f, 0.f, 0.f);

    for (int r = 0; r < K; ++r) {
        const int rowpix = (ys + r * DIL) * WW + xs;
        const float* krow = kb + (size_t)rowpix * DHEAD;
        const float* vrow = vb + (size_t)rowpix * DHEAD;
        float4 kbuf[K], vbuf[K];
#pragma unroll
        for (int c = 0; c < K; ++c)
            kbuf[c] = *reinterpret_cast<const float4*>(krow + c * (DIL * DHEAD));
#pragma unroll
        for (int c = 0; c < K; ++c)
            vbuf[c] = *reinterpret_cast<const float4*>(vrow + c * (DIL * DHEAD));

        float sc[K];
#pragma unroll
        for (int c = 0; c < K; ++c) {
            float d = DOT4(kbuf[c], qr);
            d += __shfl_xor(d, 1);
            d += __shfl_xor(d, 2);
            d += __shfl_xor(d, 4);    // full 32-d dot in all 8 d-lanes
            sc[c] = d;
        }
        float rm = sc[0];
#pragma unroll
        for (int c = 1; c < K; ++c) rm = fmaxf(rm, sc[c]);
        const float nm = fmaxf(m, rm);
        const float alpha = __expf(m - nm);
        s *= alpha;
        o.x *= alpha; o.y *= alpha; o.z *= alpha; o.w *= alpha;
        m = nm;
#pragma unroll
        for (int c = 0; c < K; ++c) {
            const float wgt = __expf(sc[c] - m);
            s += wgt;
            o.x = fmaf(wgt, vbuf[c].x, o.x);
            o.y = fmaf(wgt, vbuf[c].y, o.y);
            o.z = fmaf(wgt, vbuf[c].z, o.z);
            o.w = fmaf(wgt, vbuf[c].w, o.w);
        }
    }
    const float inv = 1.f / s;
    o.x *= inv; o.y *= inv; o.z *= inv; o.w *= inv;
    if (OUT_CM) {
        float* op = out + ((size_t)bn * DHEAD + dg * 4) * NPIX + yx;
        op[0] = o.x; op[NPIX] = o.y; op[2 * NPIX] = o.z; op[3 * NPIX] = o.w;
    } else {
        *reinterpret_cast<float4*>(
            out + ((size_t)bn * NPIX + yx) * DHEAD + dg * 4) = o;
    }
}

extern "C" void kernel_launch(void* const* d_in, const int* in_sizes, int n_in,
                              void* d_out, int out_size, void* d_ws, size_t ws_size,
                              hipStream_t stream)
{
    const float* x      = (const float*)d_in[0];
    const float* qkv_w  = (const float*)d_in[1];
    const float* qkv_b  = (const float*)d_in[2];
    const float* lepe_w = (const float*)d_in[3];
    const float* lepe_b = (const float*)d_in[4];
    const float* out_w  = (const float*)d_in[5];
    const float* out_b  = (const float*)d_in[6];
    float* out = (float*)d_out;

    const size_t ESZ = (size_t)BATCH * EDIM * NPIX;   // 1,204,224 floats
    float* ws   = (float*)d_ws;
    float* q_pm = ws;              // (b,n,yx,32)
    float* k_pm = q_pm + ESZ;
    float* v_pm = k_pm + ESZ;      // dead after pass 1 -> reused as v2_cm
    float* v_cm = v_pm + ESZ;      // (b,192,yx) for LePE
    float* lepe = v_cm + ESZ;
    float* v1   = lepe + ESZ;      // pass-1 output, pixel-major
    float* v2   = v_pm;            // pass-2 output, channel-major (alias)

    const int ptiles = (NPIX + 511) / 512;   // 7

    // 1) qkv projection: o-group fastest (L2/L3-shared pixel tile)
    dim3 gq((3 * EDIM) / 8, ptiles, BATCH);  // 72 x 7 x 2
    qkv_conv_kernel<<<gq, 256, 0, stream>>>(x, qkv_w, qkv_b, q_pm, k_pm, v_pm, v_cm);

    // 2) LePE depthwise 5x5
    const int lepe_threads = BATCH * EDIM * NPIX;
    lepe_kernel<<<(lepe_threads + 255) / 256, 256, 0, stream>>>(v_cm, lepe_w, lepe_b, lepe);

    // 3) na2d pass 1: K=7, dil=1, pixel-major out
    const int attn_blocks = (BATCH * NHEAD * NPIX * 8) / 256;   // 1176
    na2d_kernel<7, 1, false><<<attn_blocks, 256, 0, stream>>>(q_pm, k_pm, v_pm, v1);

    // 4) na2d pass 2: K=9, dil=6, channel-major out (into v_pm's storage)
    na2d_kernel<9, 6, true><<<attn_blocks, 256, 0, stream>>>(q_pm, k_pm, v1, v2);

    // 5) output projection on (v2 + lepe), o-group fastest
    dim3 go(EDIM / 8, ptiles, BATCH);        // 24 x 7 x 2
    out_conv_kernel<<<go, 256, 0, stream>>>(v2, lepe, out_w, out_b, out);
}